// Round 3
// baseline (305.121 us; speedup 1.0000x reference)
//
#include <hip/hip_runtime.h>

// LSTM: B=4096, T=512, INPUT=1, HIDDEN=32, OUTPUT=1 (fp32)
// One 64-lane wave per block handles 2 batch elements (one per 32-lane half).
// Lane j owns hidden unit j: 4 recurrent weight rows (128 fp32 = 64 float2)
// held in VGPRs — __launch_bounds__(64,2) raises the VGPR cap to 256 so they
// are truly resident (round-2's 92-VGPR allocation spilled them to scratch).
// Gate dot-products use v_pk_fma_f32 (packed fp32: 2 MACs/inst).
// log2(e) is folded into W/b at load time: every activation is
// rcp(1 + exp2(-a)) — v_exp_f32 with free neg modifier.
// h is exchanged through a per-half LDS row; barrier-free (intra-wave DS is
// in-order; compiler memory fence prevents illegal hoisting).

#define HID 32
#define TSTEPS 512
#define BPW 2            // batch elements per wave/block
#define BLOCK 64
#define L2E 1.44269504088896340736f

__device__ __forceinline__ float2 pk_fma(float2 a, float2 b, float2 c) {
    float2 d;
    asm("v_pk_fma_f32 %0, %1, %2, %3" : "=v"(d) : "v"(a), "v"(b), "v"(c));
    return d;
}
__device__ __forceinline__ float rcp_fast(float x) {
    return __builtin_amdgcn_rcpf(x);            // v_rcp_f32
}
__device__ __forceinline__ float exp2_fast(float x) {
    return __builtin_amdgcn_exp2f(x);           // v_exp_f32
}
// a is pre-scaled by log2(e): sigmoid(a/L2E)
__device__ __forceinline__ float sigmoid_l2(float a) {
    return rcp_fast(1.0f + exp2_fast(-a));
}
// a is pre-scaled by 2*log2(e): tanh(a/(2*L2E))
__device__ __forceinline__ float tanh_l2(float a) {
    return fmaf(2.0f, rcp_fast(1.0f + exp2_fast(-a)), -1.0f);
}

__global__ __launch_bounds__(BLOCK, 2)
void lstm_fused_kernel(const float* __restrict__ x,
                       const float* __restrict__ W_ih,
                       const float* __restrict__ W_hh,
                       const float* __restrict__ b_ih,
                       const float* __restrict__ b_hh,
                       const float* __restrict__ W_fc,
                       const float* __restrict__ b_fc,
                       float* __restrict__ out)
{
    __shared__ __align__(16) float x_s[BPW * TSTEPS];   // 4 KiB
    __shared__ __align__(16) float h_s[BPW][HID];       // 256 B

    const int tid = threadIdx.x;
    const int lb  = tid >> 5;        // local batch 0..1 (half-wave)
    const int j   = tid & 31;        // hidden unit
    const int b0  = blockIdx.x * BPW;

    // ---- stage x for this wave's 2 batch rows (coalesced float4) ----
    {
        const float4* xsrc = reinterpret_cast<const float4*>(x + (size_t)b0 * TSTEPS);
        float4* xdst = reinterpret_cast<float4*>(x_s);
        #pragma unroll
        for (int k = 0; k < (BPW * TSTEPS) / (4 * BLOCK); ++k)
            xdst[tid + k * BLOCK] = xsrc[tid + k * BLOCK];
    }

    // ---- per-unit weights into registers (float2 pairs, pre-scaled) ----
    // gate 0=i, 1=f, 2=g, 3=o ; scale L2E for i/f/o, 2*L2E for g
    float2 w0[HID/2], w1[HID/2], w2[HID/2], w3[HID/2];
    {
        const float4* r0 = reinterpret_cast<const float4*>(W_hh + (size_t)(0 * HID + j) * HID);
        const float4* r1 = reinterpret_cast<const float4*>(W_hh + (size_t)(1 * HID + j) * HID);
        const float4* r2 = reinterpret_cast<const float4*>(W_hh + (size_t)(2 * HID + j) * HID);
        const float4* r3 = reinterpret_cast<const float4*>(W_hh + (size_t)(3 * HID + j) * HID);
        #pragma unroll
        for (int k = 0; k < HID / 4; ++k) {
            float4 v;
            v = r0[k]; w0[2*k] = make_float2(v.x*L2E, v.y*L2E);
                       w0[2*k+1] = make_float2(v.z*L2E, v.w*L2E);
            v = r1[k]; w1[2*k] = make_float2(v.x*L2E, v.y*L2E);
                       w1[2*k+1] = make_float2(v.z*L2E, v.w*L2E);
            v = r2[k]; w2[2*k] = make_float2(v.x*2.0f*L2E, v.y*2.0f*L2E);
                       w2[2*k+1] = make_float2(v.z*2.0f*L2E, v.w*2.0f*L2E);
            v = r3[k]; w3[2*k] = make_float2(v.x*L2E, v.y*L2E);
                       w3[2*k+1] = make_float2(v.z*L2E, v.w*L2E);
        }
    }
    const float wih0 = W_ih[j]         * L2E;
    const float wih1 = W_ih[HID + j]   * L2E;
    const float wih2 = W_ih[2*HID + j] * 2.0f * L2E;
    const float wih3 = W_ih[3*HID + j] * L2E;
    const float bs0  = (b_ih[j]         + b_hh[j])         * L2E;
    const float bs1  = (b_ih[HID + j]   + b_hh[HID + j])   * L2E;
    const float bs2  = (b_ih[2*HID + j] + b_hh[2*HID + j]) * 2.0f * L2E;
    const float bs3  = (b_ih[3*HID + j] + b_hh[3*HID + j]) * L2E;

    // ---- init state ----
    h_s[lb][j] = 0.0f;
    float c = 0.0f;
    float hcur = 0.0f;
    __syncthreads();   // single-wave block: orders staging

    // ---- recurrence: no barriers (intra-wave LDS is in-order) ----
    #pragma unroll 1
    for (int t = 0; t < TSTEPS; ++t) {
        const float xv = x_s[lb * TSTEPS + t];

        float2 acc0 = make_float2(fmaf(xv, wih0, bs0), 0.0f);
        float2 acc1 = make_float2(fmaf(xv, wih1, bs1), 0.0f);
        float2 acc2 = make_float2(fmaf(xv, wih2, bs2), 0.0f);
        float2 acc3 = make_float2(fmaf(xv, wih3, bs3), 0.0f);

        const float4* hr = reinterpret_cast<const float4*>(&h_s[lb][0]);
        #pragma unroll
        for (int k = 0; k < HID / 4; ++k) {
            float4 hv = hr[k];
            float2 hA = make_float2(hv.x, hv.y);
            float2 hB = make_float2(hv.z, hv.w);
            acc0 = pk_fma(hA, w0[2*k], acc0);
            acc1 = pk_fma(hA, w1[2*k], acc1);
            acc2 = pk_fma(hA, w2[2*k], acc2);
            acc3 = pk_fma(hA, w3[2*k], acc3);
            acc0 = pk_fma(hB, w0[2*k+1], acc0);
            acc1 = pk_fma(hB, w1[2*k+1], acc1);
            acc2 = pk_fma(hB, w2[2*k+1], acc2);
            acc3 = pk_fma(hB, w3[2*k+1], acc3);
        }
        const float a0 = acc0.x + acc0.y;
        const float a1 = acc1.x + acc1.y;
        const float a2 = acc2.x + acc2.y;
        const float a3 = acc3.x + acc3.y;

        const float ig = sigmoid_l2(a0);
        const float fg = sigmoid_l2(a1);
        const float gg = tanh_l2(a2);
        const float og = sigmoid_l2(a3);
        c    = fmaf(fg, c, ig * gg);
        hcur = og * tanh_l2((2.0f * L2E) * c);

        h_s[lb][j] = hcur;
        // compiler fence: forbid hoisting next iteration's h reads above this
        // write (HW: same-wave DS ops complete in order, no barrier needed)
        asm volatile("" ::: "memory");
    }

    // ---- final FC: out[b] = dot(h_T, W_fc) + b_fc ----
    float p = hcur * W_fc[j];
    #pragma unroll
    for (int off = 16; off >= 1; off >>= 1)
        p += __shfl_xor(p, off);   // xor masks <=16 stay within each half
    if (j == 0)
        out[b0 + lb] = p + b_fc[0];
}

extern "C" void kernel_launch(void* const* d_in, const int* in_sizes, int n_in,
                              void* d_out, int out_size, void* d_ws, size_t ws_size,
                              hipStream_t stream) {
    const float* x    = (const float*)d_in[0];
    const float* W_ih = (const float*)d_in[1];
    const float* W_hh = (const float*)d_in[2];
    const float* b_ih = (const float*)d_in[3];
    const float* b_hh = (const float*)d_in[4];
    const float* W_fc = (const float*)d_in[5];
    const float* b_fc = (const float*)d_in[6];
    float* out = (float*)d_out;

    const int B = in_sizes[0] / TSTEPS;   // 4096 (INPUT=1)
    const int grid = B / BPW;             // 2048 blocks, 1 wave each
    lstm_fused_kernel<<<grid, BLOCK, 0, stream>>>(x, W_ih, W_hh, b_ih, b_hh,
                                                  W_fc, b_fc, out);
}

// Round 4
// 278.390 us; speedup vs baseline: 1.0960x; 1.0960x over previous
//
#include <hip/hip_runtime.h>

// LSTM: B=4096, T=512, INPUT=1, HIDDEN=32, OUTPUT=1 (fp32)
// One 64-lane wave per block handles 2 batch elements (one per 32-lane half).
// Lane j owns hidden unit j: 4 recurrent weight rows (128 fp32) in VGPRs.
// KEY FIX vs rounds 1-3: weights are made register-opaque via a no-op asm
// ("+v") after loading, so the per-step memory clobber (required for the LDS
// h exchange) cannot force the compiler to re-load them from memory each
// timestep (VGPR_Count was 84 in all prior rounds => weights were NOT
// resident; they were refetched every step).
// log2(e) folded into W/b at load: activations are rcp(1+exp2(-a)).
// h exchange: per-half LDS row, barrier-free (same-wave DS ops are in-order).

#define HID 32
#define TSTEPS 512
#define BPW 2            // batch elements per wave/block
#define BLOCK 64
#define L2E 1.44269504088896340736f

// make a float's provenance opaque: compiler must keep it in a VGPR
#define OPAQUE(v) asm("" : "+v"(v))

__device__ __forceinline__ float rcp_fast(float x) {
    return __builtin_amdgcn_rcpf(x);            // v_rcp_f32
}
__device__ __forceinline__ float exp2_fast(float x) {
    return __builtin_amdgcn_exp2f(x);           // v_exp_f32
}
// a pre-scaled by log2(e): sigmoid(a/L2E)
__device__ __forceinline__ float sigmoid_l2(float a) {
    return rcp_fast(1.0f + exp2_fast(-a));
}
// a pre-scaled by 2*log2(e): tanh(a/(2*L2E))
__device__ __forceinline__ float tanh_l2(float a) {
    return fmaf(2.0f, rcp_fast(1.0f + exp2_fast(-a)), -1.0f);
}

__global__ __launch_bounds__(BLOCK, 2)
void lstm_fused_kernel(const float* __restrict__ x,
                       const float* __restrict__ W_ih,
                       const float* __restrict__ W_hh,
                       const float* __restrict__ b_ih,
                       const float* __restrict__ b_hh,
                       const float* __restrict__ W_fc,
                       const float* __restrict__ b_fc,
                       float* __restrict__ out)
{
    __shared__ __align__(16) float x_s[BPW * TSTEPS];   // 4 KiB
    __shared__ __align__(16) float h_s[BPW][HID];       // 256 B

    const int tid = threadIdx.x;
    const int lb  = tid >> 5;        // local batch 0..1 (half-wave)
    const int j   = tid & 31;        // hidden unit
    const int b0  = blockIdx.x * BPW;

    // ---- stage x for this wave's 2 batch rows (coalesced float4) ----
    {
        const float4* xsrc = reinterpret_cast<const float4*>(x + (size_t)b0 * TSTEPS);
        float4* xdst = reinterpret_cast<float4*>(x_s);
        #pragma unroll
        for (int k = 0; k < (BPW * TSTEPS) / (4 * BLOCK); ++k)
            xdst[tid + k * BLOCK] = xsrc[tid + k * BLOCK];
    }

    // ---- per-unit weights into registers, pre-scaled, made opaque ----
    // gate 0=i, 1=f, 2=g, 3=o ; scale L2E for i/f/o, 2*L2E for g
    float w0[HID], w1[HID], w2[HID], w3[HID];
    {
        const float4* r0 = reinterpret_cast<const float4*>(W_hh + (size_t)(0 * HID + j) * HID);
        const float4* r1 = reinterpret_cast<const float4*>(W_hh + (size_t)(1 * HID + j) * HID);
        const float4* r2 = reinterpret_cast<const float4*>(W_hh + (size_t)(2 * HID + j) * HID);
        const float4* r3 = reinterpret_cast<const float4*>(W_hh + (size_t)(3 * HID + j) * HID);
        #pragma unroll
        for (int k = 0; k < HID / 4; ++k) {
            float4 v;
            v = r0[k]; w0[4*k]=v.x*L2E; w0[4*k+1]=v.y*L2E; w0[4*k+2]=v.z*L2E; w0[4*k+3]=v.w*L2E;
            v = r1[k]; w1[4*k]=v.x*L2E; w1[4*k+1]=v.y*L2E; w1[4*k+2]=v.z*L2E; w1[4*k+3]=v.w*L2E;
            v = r2[k]; w2[4*k]=v.x*2.0f*L2E; w2[4*k+1]=v.y*2.0f*L2E; w2[4*k+2]=v.z*2.0f*L2E; w2[4*k+3]=v.w*2.0f*L2E;
            v = r3[k]; w3[4*k]=v.x*L2E; w3[4*k+1]=v.y*L2E; w3[4*k+2]=v.z*L2E; w3[4*k+3]=v.w*L2E;
        }
        #pragma unroll
        for (int m = 0; m < HID; ++m) {
            OPAQUE(w0[m]); OPAQUE(w1[m]); OPAQUE(w2[m]); OPAQUE(w3[m]);
        }
    }
    float wih0 = W_ih[j]         * L2E;
    float wih1 = W_ih[HID + j]   * L2E;
    float wih2 = W_ih[2*HID + j] * 2.0f * L2E;
    float wih3 = W_ih[3*HID + j] * L2E;
    float bs0  = (b_ih[j]         + b_hh[j])         * L2E;
    float bs1  = (b_ih[HID + j]   + b_hh[HID + j])   * L2E;
    float bs2  = (b_ih[2*HID + j] + b_hh[2*HID + j]) * 2.0f * L2E;
    float bs3  = (b_ih[3*HID + j] + b_hh[3*HID + j]) * L2E;
    OPAQUE(wih0); OPAQUE(wih1); OPAQUE(wih2); OPAQUE(wih3);
    OPAQUE(bs0);  OPAQUE(bs1);  OPAQUE(bs2);  OPAQUE(bs3);

    // ---- init state ----
    h_s[lb][j] = 0.0f;
    float c = 0.0f;
    float hcur = 0.0f;
    __syncthreads();   // single-wave block: orders staging

    // ---- recurrence: no barriers (same-wave DS ops execute in order) ----
    #pragma unroll 1
    for (int t = 0; t < TSTEPS; ++t) {
        const float xv = x_s[lb * TSTEPS + t];

        float a0 = fmaf(xv, wih0, bs0);
        float a1 = fmaf(xv, wih1, bs1);
        float a2 = fmaf(xv, wih2, bs2);
        float a3 = fmaf(xv, wih3, bs3);

        const float4* hr = reinterpret_cast<const float4*>(&h_s[lb][0]);
        #pragma unroll
        for (int k = 0; k < HID / 4; ++k) {
            float4 hv = hr[k];
            a0 = fmaf(hv.x, w0[4*k  ], a0);
            a1 = fmaf(hv.x, w1[4*k  ], a1);
            a2 = fmaf(hv.x, w2[4*k  ], a2);
            a3 = fmaf(hv.x, w3[4*k  ], a3);
            a0 = fmaf(hv.y, w0[4*k+1], a0);
            a1 = fmaf(hv.y, w1[4*k+1], a1);
            a2 = fmaf(hv.y, w2[4*k+1], a2);
            a3 = fmaf(hv.y, w3[4*k+1], a3);
            a0 = fmaf(hv.z, w0[4*k+2], a0);
            a1 = fmaf(hv.z, w1[4*k+2], a1);
            a2 = fmaf(hv.z, w2[4*k+2], a2);
            a3 = fmaf(hv.z, w3[4*k+2], a3);
            a0 = fmaf(hv.w, w0[4*k+3], a0);
            a1 = fmaf(hv.w, w1[4*k+3], a1);
            a2 = fmaf(hv.w, w2[4*k+3], a2);
            a3 = fmaf(hv.w, w3[4*k+3], a3);
        }

        const float ig = sigmoid_l2(a0);
        const float fg = sigmoid_l2(a1);
        const float gg = tanh_l2(a2);
        const float og = sigmoid_l2(a3);
        c    = fmaf(fg, c, ig * gg);
        hcur = og * tanh_l2((2.0f * L2E) * c);

        h_s[lb][j] = hcur;
        // forbid hoisting next iteration's h reads above this write
        // (HW: same-wave DS ops complete in order; weights are asm-opaque
        //  so this clobber cannot force their re-load from memory)
        asm volatile("" ::: "memory");
    }

    // ---- final FC: out[b] = dot(h_T, W_fc) + b_fc ----
    float p = hcur * W_fc[j];
    #pragma unroll
    for (int off = 16; off >= 1; off >>= 1)
        p += __shfl_xor(p, off);   // xor masks <=16 stay within each half
    if (j == 0)
        out[b0 + lb] = p + b_fc[0];
}

extern "C" void kernel_launch(void* const* d_in, const int* in_sizes, int n_in,
                              void* d_out, int out_size, void* d_ws, size_t ws_size,
                              hipStream_t stream) {
    const float* x    = (const float*)d_in[0];
    const float* W_ih = (const float*)d_in[1];
    const float* W_hh = (const float*)d_in[2];
    const float* b_ih = (const float*)d_in[3];
    const float* b_hh = (const float*)d_in[4];
    const float* W_fc = (const float*)d_in[5];
    const float* b_fc = (const float*)d_in[6];
    float* out = (float*)d_out;

    const int B = in_sizes[0] / TSTEPS;   // 4096 (INPUT=1)
    const int grid = B / BPW;             // 2048 blocks, 1 wave each
    lstm_fused_kernel<<<grid, BLOCK, 0, stream>>>(x, W_ih, W_hh, b_ih, b_hh,
                                                  W_fc, b_fc, out);
}